// Round 15
// baseline (59.002 us; speedup 1.0000x reference)
//
#include <hip/hip_runtime.h>
#include <math.h>

#define NT 256
#define NBSPLIT 4
#define NB (16 / NBSPLIT)   // 4 batches/thread, processed as 2 interleaved PAIRS
#define NSWEEPS 4           // fallback kernel only

__device__ __forceinline__ float fsqrt_(float x) { return __builtin_amdgcn_sqrtf(x); }
__device__ __forceinline__ float frcp_(float x)  { return __builtin_amdgcn_rcpf(x); }
__device__ __forceinline__ float frsq_(float x)  { return __builtin_amdgcn_rsqf(x); }

// maxd==6 specialized: dual-chain POLAR-NEWTON (r15 = r14 + jo/wgt in LDS).
// r14 failed at VGPR=132 (4 over the 128 occupancy cliff -> 3 waves/SIMD,
// dur 59us). Fix: jo[6]+wgt[6] (12 persistent VGPRs) move to LDS
// thread-private columns (conflict-free, no barriers; LDS 31KB/block,
// 4 blocks/CU = 124KB < 160KB — not binding). Dual chains give the ILP
// that the serial cof->det->rcp->sqrt chains need at the flat 4-waves/SIMD
// plateau (VGPR 65..128, m69).
// Flip (reference flips LARGEST singular column when det(A)<0, ~6% lanes):
// v1 = argmax eigvec of M=A^T A via plain quadratic (lam3 quartically small
// for flip lanes) + rank-1 projector G = M^2 - sft*M, hoisted BEFORE Newton,
// applied branchlessly X -= s*(X v1) v1^T (s = det<0 ? 2 : 0).
// Newton: 2 Frobenius-scaled + 2 unscaled, IN PLACE on A (scale-invariant).
// Degenerate corners (A~0): NaN -> fminf(NaN,1)=1, error <= 2/n.
// NO launch_bounds min-waves pin (r4/r5: catastrophic spill). No atomics (r11).
__global__ __launch_bounds__(NT) void arap_fused6(
    const float* __restrict__ pred,      // (B, 3, n)
    const int*   __restrict__ adj_idx,   // (n, 6)
    const float* __restrict__ adj_w,     // (n, 6)
    const float* __restrict__ tevT,      // (n, 3, 6)
    float* __restrict__ partials,        // (B, nblk_x)
    int n, int nblk_x)
{
    __shared__ float tvs[18][NT];        // tevT row      (thread-private col)
    __shared__ int   jos[6][NT];         // adj indices   (thread-private col)
    __shared__ float wgs[6][NT];         // adj weights   (thread-private col)
    __shared__ float sm[NT / 64][NB];

    const int tid = threadIdx.x;
    const int v = blockIdx.x * NT + tid;
    const bool active = (v < n);
    const int vc = active ? v : 0;
    const int b0 = blockIdx.y * NB;

    {
        const int2* ai = (const int2*)(adj_idx + (size_t)vc * 6);
        int2 q0 = ai[0], q1 = ai[1], q2 = ai[2];
        jos[0][tid] = q0.x; jos[1][tid] = q0.y; jos[2][tid] = q1.x;
        jos[3][tid] = q1.y; jos[4][tid] = q2.x; jos[5][tid] = q2.y;
        const float2* aw = (const float2*)(adj_w + (size_t)vc * 6);
        float2 w0 = aw[0], w1 = aw[1], w2 = aw[2];
        wgs[0][tid] = w0.x; wgs[1][tid] = w0.y; wgs[2][tid] = w1.x;
        wgs[3][tid] = w1.y; wgs[4][tid] = w2.x; wgs[5][tid] = w2.y;
        const float2* tv = (const float2*)(tevT + (size_t)vc * 18);
        #pragma unroll
        for (int i = 0; i < 9; ++i) {
            float2 t = tv[i];
            tvs[2 * i][tid]     = t.x;
            tvs[2 * i + 1][tid] = t.y;
        }
        // no __syncthreads: each thread only reads its own column
    }

    const int lane = tid & 63, wid = tid >> 6;

    #pragma unroll 1
    for (int pi = 0; pi < NB / 2; ++pi) {
        const float* __restrict__ pA = pred + (size_t)(b0 + 2 * pi) * 3 * n;
        const float* __restrict__ pB = pA + (size_t)3 * n;
        const float pax = pA[vc], pay = pA[n + vc], paz = pA[2 * n + vc];
        const float pbx = pB[vc], pby = pB[n + vc], pbz = pB[2 * n + vc];

        // ---- Pass 1 (both chains): X = A = pred_ev @ (w * tevT^T) ----
        float xa00 = 0.f, xa01 = 0.f, xa02 = 0.f;
        float xa10 = 0.f, xa11 = 0.f, xa12 = 0.f;
        float xa20 = 0.f, xa21 = 0.f, xa22 = 0.f;
        float xb00 = 0.f, xb01 = 0.f, xb02 = 0.f;
        float xb10 = 0.f, xb11 = 0.f, xb12 = 0.f;
        float xb20 = 0.f, xb21 = 0.f, xb22 = 0.f;
        #pragma unroll
        for (int k = 0; k < 6; ++k) {
            int j = jos[k][tid];
            float t0 = tvs[k][tid], t1 = tvs[6 + k][tid], t2 = tvs[12 + k][tid];
            float w = wgs[k][tid];
            float ax = pA[j] - pax, ay = pA[n + j] - pay, az = pA[2 * n + j] - paz;
            float bx = pB[j] - pbx, by = pB[n + j] - pby, bz = pB[2 * n + j] - pbz;
            float fax = w * ax, fay = w * ay, faz = w * az;
            float fbx = w * bx, fby = w * by, fbz = w * bz;
            xa00 += fax * t0; xa01 += fax * t1; xa02 += fax * t2;
            xa10 += fay * t0; xa11 += fay * t1; xa12 += fay * t2;
            xa20 += faz * t0; xa21 += faz * t1; xa22 += faz * t2;
            xb00 += fbx * t0; xb01 += fbx * t1; xb02 += fbx * t2;
            xb10 += fby * t0; xb11 += fby * t1; xb12 += fby * t2;
            xb20 += fbz * t0; xb21 += fbz * t1; xb22 += fbz * t2;
        }

        float dta = xa00 * (xa11 * xa22 - xa21 * xa12)
                  - xa10 * (xa01 * xa22 - xa21 * xa02)
                  + xa20 * (xa01 * xa12 - xa11 * xa02);
        float dtb = xb00 * (xb11 * xb22 - xb21 * xb12)
                  - xb10 * (xb01 * xb22 - xb21 * xb02)
                  + xb20 * (xb01 * xb12 - xb11 * xb02);

        // ---- hoisted flip precompute (trimmed), chain A ----
        float vax, vay, vaz, sa;
        {
            float m00 = xa00 * xa00 + xa10 * xa10 + xa20 * xa20;
            float m01 = xa00 * xa01 + xa10 * xa11 + xa20 * xa21;
            float m02 = xa00 * xa02 + xa10 * xa12 + xa20 * xa22;
            float m11 = xa01 * xa01 + xa11 * xa11 + xa21 * xa21;
            float m12 = xa01 * xa02 + xa11 * xa12 + xa21 * xa22;
            float m22 = xa02 * xa02 + xa12 * xa12 + xa22 * xa22;
            float c2 = m00 + m11 + m22;
            float c1 = m00 * m11 - m01 * m01 + m00 * m22 - m02 * m02
                     + m11 * m22 - m12 * m12;
            float disc = fmaxf(c2 * c2 - 4.0f * c1, 0.0f);
            float lam = 0.5f * (c2 + fsqrt_(disc));
            float sft = c2 - lam;
            float q00 = m00 * m00 + m01 * m01 + m02 * m02 - sft * m00;
            float q01 = m00 * m01 + m01 * m11 + m02 * m12 - sft * m01;
            float q02 = m00 * m02 + m01 * m12 + m02 * m22 - sft * m02;
            float q11 = m01 * m01 + m11 * m11 + m12 * m12 - sft * m11;
            float q12 = m01 * m02 + m11 * m12 + m12 * m22 - sft * m12;
            float q22 = m02 * m02 + m12 * m12 + m22 * m22 - sft * m22;
            if (q00 >= q11 && q00 >= q22)      { vax = q00; vay = q01; vaz = q02; }
            else if (q11 >= q22)               { vax = q01; vay = q11; vaz = q12; }
            else                               { vax = q02; vay = q12; vaz = q22; }
            float inv = frsq_(fmaxf(vax * vax + vay * vay + vaz * vaz, 1e-30f));
            vax *= inv; vay *= inv; vaz *= inv;
            sa = (dta < 0.0f) ? 2.0f : 0.0f;
        }
        // ---- hoisted flip precompute (trimmed), chain B ----
        float vbx, vby, vbz, sb;
        {
            float m00 = xb00 * xb00 + xb10 * xb10 + xb20 * xb20;
            float m01 = xb00 * xb01 + xb10 * xb11 + xb20 * xb21;
            float m02 = xb00 * xb02 + xb10 * xb12 + xb20 * xb22;
            float m11 = xb01 * xb01 + xb11 * xb11 + xb21 * xb21;
            float m12 = xb01 * xb02 + xb11 * xb12 + xb21 * xb22;
            float m22 = xb02 * xb02 + xb12 * xb12 + xb22 * xb22;
            float c2 = m00 + m11 + m22;
            float c1 = m00 * m11 - m01 * m01 + m00 * m22 - m02 * m02
                     + m11 * m22 - m12 * m12;
            float disc = fmaxf(c2 * c2 - 4.0f * c1, 0.0f);
            float lam = 0.5f * (c2 + fsqrt_(disc));
            float sft = c2 - lam;
            float q00 = m00 * m00 + m01 * m01 + m02 * m02 - sft * m00;
            float q01 = m00 * m01 + m01 * m11 + m02 * m12 - sft * m01;
            float q02 = m00 * m02 + m01 * m12 + m02 * m22 - sft * m02;
            float q11 = m01 * m01 + m11 * m11 + m12 * m12 - sft * m11;
            float q12 = m01 * m02 + m11 * m12 + m12 * m22 - sft * m12;
            float q22 = m02 * m02 + m12 * m12 + m22 * m22 - sft * m22;
            if (q00 >= q11 && q00 >= q22)      { vbx = q00; vby = q01; vbz = q02; }
            else if (q11 >= q22)               { vbx = q01; vby = q11; vbz = q12; }
            else                               { vbx = q02; vby = q12; vbz = q22; }
            float inv = frsq_(fmaxf(vbx * vbx + vby * vby + vbz * vbz, 1e-30f));
            vbx *= inv; vby *= inv; vbz *= inv;
            sb = (dtb < 0.0f) ? 2.0f : 0.0f;
        }

        // ---- scaled Newton, IN PLACE, both chains interleaved ----
        #pragma unroll
        for (int it = 0; it < 2; ++it) {
            float ca00 = xa11 * xa22 - xa21 * xa12;
            float ca01 = xa12 * xa20 - xa10 * xa22;
            float ca02 = xa10 * xa21 - xa11 * xa20;
            float ca10 = xa02 * xa21 - xa01 * xa22;
            float ca11 = xa00 * xa22 - xa02 * xa20;
            float ca12 = xa01 * xa20 - xa00 * xa21;
            float ca20 = xa01 * xa12 - xa02 * xa11;
            float ca21 = xa02 * xa10 - xa00 * xa12;
            float ca22 = xa00 * xa11 - xa01 * xa10;
            float cb00 = xb11 * xb22 - xb21 * xb12;
            float cb01 = xb12 * xb20 - xb10 * xb22;
            float cb02 = xb10 * xb21 - xb11 * xb20;
            float cb10 = xb02 * xb21 - xb01 * xb22;
            float cb11 = xb00 * xb22 - xb02 * xb20;
            float cb12 = xb01 * xb20 - xb00 * xb21;
            float cb20 = xb01 * xb12 - xb02 * xb11;
            float cb21 = xb02 * xb10 - xb00 * xb12;
            float cb22 = xb00 * xb11 - xb01 * xb10;
            float da = xa00 * ca00 + xa01 * ca01 + xa02 * ca02;
            float db = xb00 * cb00 + xb01 * cb01 + xb02 * cb02;
            float nXa = xa00 * xa00 + xa01 * xa01 + xa02 * xa02
                      + xa10 * xa10 + xa11 * xa11 + xa12 * xa12
                      + xa20 * xa20 + xa21 * xa21 + xa22 * xa22;
            float nXb = xb00 * xb00 + xb01 * xb01 + xb02 * xb02
                      + xb10 * xb10 + xb11 * xb11 + xb12 * xb12
                      + xb20 * xb20 + xb21 * xb21 + xb22 * xb22;
            float nCa = ca00 * ca00 + ca01 * ca01 + ca02 * ca02
                      + ca10 * ca10 + ca11 * ca11 + ca12 * ca12
                      + ca20 * ca20 + ca21 * ca21 + ca22 * ca22;
            float nCb = cb00 * cb00 + cb01 * cb01 + cb02 * cb02
                      + cb10 * cb10 + cb11 * cb11 + cb12 * cb12
                      + cb20 * cb20 + cb21 * cb21 + cb22 * cb22;
            float ra = nCa * frcp_(da * da * nXa);
            float rb = nCb * frcp_(db * db * nXb);
            float mua = fsqrt_(fsqrt_(ra));
            float mub = fsqrt_(fsqrt_(rb));
            float f1a = 0.5f * mua, f2a = 0.5f * frcp_(mua * da);
            float f1b = 0.5f * mub, f2b = 0.5f * frcp_(mub * db);
            xa00 = f1a * xa00 + f2a * ca00;
            xa01 = f1a * xa01 + f2a * ca01;
            xa02 = f1a * xa02 + f2a * ca02;
            xa10 = f1a * xa10 + f2a * ca10;
            xa11 = f1a * xa11 + f2a * ca11;
            xa12 = f1a * xa12 + f2a * ca12;
            xa20 = f1a * xa20 + f2a * ca20;
            xa21 = f1a * xa21 + f2a * ca21;
            xa22 = f1a * xa22 + f2a * ca22;
            xb00 = f1b * xb00 + f2b * cb00;
            xb01 = f1b * xb01 + f2b * cb01;
            xb02 = f1b * xb02 + f2b * cb02;
            xb10 = f1b * xb10 + f2b * cb10;
            xb11 = f1b * xb11 + f2b * cb11;
            xb12 = f1b * xb12 + f2b * cb12;
            xb20 = f1b * xb20 + f2b * cb20;
            xb21 = f1b * xb21 + f2b * cb21;
            xb22 = f1b * xb22 + f2b * cb22;
        }
        // ---- unscaled Newton, both chains ----
        #pragma unroll
        for (int it = 0; it < 2; ++it) {
            float ca00 = xa11 * xa22 - xa21 * xa12;
            float ca01 = xa12 * xa20 - xa10 * xa22;
            float ca02 = xa10 * xa21 - xa11 * xa20;
            float ca10 = xa02 * xa21 - xa01 * xa22;
            float ca11 = xa00 * xa22 - xa02 * xa20;
            float ca12 = xa01 * xa20 - xa00 * xa21;
            float ca20 = xa01 * xa12 - xa02 * xa11;
            float ca21 = xa02 * xa10 - xa00 * xa12;
            float ca22 = xa00 * xa11 - xa01 * xa10;
            float cb00 = xb11 * xb22 - xb21 * xb12;
            float cb01 = xb12 * xb20 - xb10 * xb22;
            float cb02 = xb10 * xb21 - xb11 * xb20;
            float cb10 = xb02 * xb21 - xb01 * xb22;
            float cb11 = xb00 * xb22 - xb02 * xb20;
            float cb12 = xb01 * xb20 - xb00 * xb21;
            float cb20 = xb01 * xb12 - xb02 * xb11;
            float cb21 = xb02 * xb10 - xb00 * xb12;
            float cb22 = xb00 * xb11 - xb01 * xb10;
            float da = xa00 * ca00 + xa01 * ca01 + xa02 * ca02;
            float db = xb00 * cb00 + xb01 * cb01 + xb02 * cb02;
            float f2a = 0.5f * frcp_(da);
            float f2b = 0.5f * frcp_(db);
            xa00 = 0.5f * xa00 + f2a * ca00;
            xa01 = 0.5f * xa01 + f2a * ca01;
            xa02 = 0.5f * xa02 + f2a * ca02;
            xa10 = 0.5f * xa10 + f2a * ca10;
            xa11 = 0.5f * xa11 + f2a * ca11;
            xa12 = 0.5f * xa12 + f2a * ca12;
            xa20 = 0.5f * xa20 + f2a * ca20;
            xa21 = 0.5f * xa21 + f2a * ca21;
            xa22 = 0.5f * xa22 + f2a * ca22;
            xb00 = 0.5f * xb00 + f2b * cb00;
            xb01 = 0.5f * xb01 + f2b * cb01;
            xb02 = 0.5f * xb02 + f2b * cb02;
            xb10 = 0.5f * xb10 + f2b * cb10;
            xb11 = 0.5f * xb11 + f2b * cb11;
            xb12 = 0.5f * xb12 + f2b * cb12;
            xb20 = 0.5f * xb20 + f2b * cb20;
            xb21 = 0.5f * xb21 + f2b * cb21;
            xb22 = 0.5f * xb22 + f2b * cb22;
        }

        // ---- branchless flips: X -= s * (X v1) v1^T ----
        {
            float ux = xa00 * vax + xa01 * vay + xa02 * vaz;
            float uy = xa10 * vax + xa11 * vay + xa12 * vaz;
            float uz = xa20 * vax + xa21 * vay + xa22 * vaz;
            ux *= sa; uy *= sa; uz *= sa;
            xa00 -= ux * vax; xa01 -= ux * vay; xa02 -= ux * vaz;
            xa10 -= uy * vax; xa11 -= uy * vay; xa12 -= uy * vaz;
            xa20 -= uz * vax; xa21 -= uz * vay; xa22 -= uz * vaz;
        }
        {
            float ux = xb00 * vbx + xb01 * vby + xb02 * vbz;
            float uy = xb10 * vbx + xb11 * vby + xb12 * vbz;
            float uz = xb20 * vbx + xb21 * vby + xb22 * vbz;
            ux *= sb; uy *= sb; uz *= sb;
            xb00 -= ux * vbx; xb01 -= ux * vby; xb02 -= ux * vbz;
            xb10 -= uy * vbx; xb11 -= uy * vby; xb12 -= uy * vbz;
            xb20 -= uz * vbx; xb21 -= uz * vby; xb22 -= uz * vbz;
        }

        // ---- Pass 2 (both chains): energy, edges re-gathered (L1/L2) ----
        float nrgA = 0.0f, nrgB = 0.0f;
        #pragma unroll
        for (int k = 0; k < 6; ++k) {
            int j = jos[k][tid];
            float t0 = tvs[k][tid], t1 = tvs[6 + k][tid], t2 = tvs[12 + k][tid];
            float ax = pA[j] - pax, ay = pA[n + j] - pay, az = pA[2 * n + j] - paz;
            float bx = pB[j] - pbx, by = pB[n + j] - pby, bz = pB[2 * n + j] - pbz;
            float qa0 = xa00 * t0 + xa01 * t1 + xa02 * t2;
            float qa1 = xa10 * t0 + xa11 * t1 + xa12 * t2;
            float qa2 = xa20 * t0 + xa21 * t1 + xa22 * t2;
            float qb0 = xb00 * t0 + xb01 * t1 + xb02 * t2;
            float qb1 = xb10 * t0 + xb11 * t1 + xb12 * t2;
            float qb2 = xb20 * t0 + xb21 * t1 + xb22 * t2;
            float dax = ax - qa0, day = ay - qa1, daz = az - qa2;
            float dbx = bx - qb0, dby = by - qb1, dbz = bz - qb2;
            float w = wgs[k][tid];
            nrgA += w * fsqrt_(dax * dax + day * day + daz * daz);
            nrgB += w * fsqrt_(dbx * dbx + dby * dby + dbz * dbz);
        }
        float valA = active ? fminf(nrgA, 1.0f) : 0.0f;
        float valB = active ? fminf(nrgB, 1.0f) : 0.0f;

        #pragma unroll
        for (int off = 32; off > 0; off >>= 1) {
            valA += __shfl_down(valA, off, 64);
            valB += __shfl_down(valB, off, 64);
        }
        if (lane == 0) { sm[wid][2 * pi] = valA; sm[wid][2 * pi + 1] = valB; }
    }

    __syncthreads();
    if (tid < NB) {
        float sacc = 0.0f;
        #pragma unroll
        for (int w = 0; w < NT / 64; ++w) sacc += sm[w][tid];
        partials[(size_t)(b0 + tid) * nblk_x + blockIdx.x] = sacc;
    }
}

// ---------------- generic fallback (Jacobi path) ----------------
__device__ __forceinline__ void jrot(float& app, float& aqq, float& apq,
                                     float& arp, float& arq,
                                     float& vp0, float& vp1, float& vp2,
                                     float& vq0, float& vq1, float& vq2)
{
    float a = apq;
    float scale = fabsf(app) + fabsf(aqq);
    if (fabsf(a) > 1e-12f * scale + 1e-35f) {
        float h = aqq - app;
        float r = fsqrt_(fmaf(h, h, 4.0f * a * a));
        float den = fabsf(h) + r;
        float t2a = (h >= 0.0f) ? 2.0f * a : -2.0f * a;
        float t = t2a * frcp_(den);
        float c = frsq_(fmaf(t, t, 1.0f));
        float s = t * c;
        app -= t * a;
        aqq += t * a;
        apq = 0.0f;
        float rp = arp, rq = arq;
        arp = c * rp - s * rq;
        arq = s * rp + c * rq;
        float x, y;
        x = vp0; y = vq0; vp0 = c * x - s * y; vq0 = s * x + c * y;
        x = vp1; y = vq1; vp1 = c * x - s * y; vq1 = s * x + c * y;
        x = vp2; y = vq2; vp2 = c * x - s * y; vq2 = s * x + c * y;
    }
}

__global__ __launch_bounds__(NT) void arap_main(
    const float* __restrict__ pred, const int* __restrict__ adj_idx,
    const float* __restrict__ adj_w, const float* __restrict__ tevT,
    const float* __restrict__ tevw, float* __restrict__ partials,
    int n, int maxd, int nblk_x)
{
    const int b = blockIdx.y;
    const float* __restrict__ predb = pred + (size_t)b * 3 * n;
    float local = 0.0f;

    for (int v = blockIdx.x * NT + threadIdx.x; v < n; v += nblk_x * NT) {
        const float p0x = predb[v];
        const float p0y = predb[n + v];
        const float p0z = predb[2 * n + v];

        float a00 = 0.f, a01 = 0.f, a02 = 0.f;
        float a10 = 0.f, a11 = 0.f, a12 = 0.f;
        float a20 = 0.f, a21 = 0.f, a22 = 0.f;
        for (int k = 0; k < maxd; ++k) {
            int j = adj_idx[v * maxd + k];
            float ex = predb[j] - p0x;
            float ey = predb[n + j] - p0y;
            float ez = predb[2 * n + j] - p0z;
            const float* tw = tevw + ((size_t)v * maxd + k) * 3;
            float t0 = tw[0], t1 = tw[1], t2 = tw[2];
            a00 += ex * t0; a01 += ex * t1; a02 += ex * t2;
            a10 += ey * t0; a11 += ey * t1; a12 += ey * t2;
            a20 += ez * t0; a21 += ez * t1; a22 += ez * t2;
        }
        const float stab = 1000.0f;
        a00 *= stab; a01 *= stab; a02 *= stab;
        a10 *= stab; a11 *= stab; a12 *= stab;
        a20 *= stab; a21 *= stab; a22 *= stab;

        float m00 = a00 * a00 + a10 * a10 + a20 * a20;
        float m01 = a00 * a01 + a10 * a11 + a20 * a21;
        float m02 = a00 * a02 + a10 * a12 + a20 * a22;
        float m11 = a01 * a01 + a11 * a11 + a21 * a21;
        float m12 = a01 * a02 + a11 * a12 + a21 * a22;
        float m22 = a02 * a02 + a12 * a12 + a22 * a22;

        float v00 = 1.f, v01 = 0.f, v02 = 0.f;
        float v10 = 0.f, v11 = 1.f, v12 = 0.f;
        float v20 = 0.f, v21 = 0.f, v22 = 1.f;
        #pragma unroll
        for (int sweep = 0; sweep < NSWEEPS; ++sweep) {
            jrot(m00, m11, m01, m02, m12, v00, v10, v20, v01, v11, v21);
            jrot(m00, m22, m02, m01, m12, v00, v10, v20, v02, v12, v22);
            jrot(m11, m22, m12, m01, m02, v01, v11, v21, v02, v12, v22);
        }

        float is0 = frsq_(fmaxf(m00, 1e-6f));
        float is1 = frsq_(fmaxf(m11, 1e-6f));
        float is2 = frsq_(fmaxf(m22, 1e-6f));
        float detA = a00 * (a11 * a22 - a21 * a12)
                   - a10 * (a01 * a22 - a21 * a02)
                   + a20 * (a01 * a12 - a11 * a02);
        float dd = detA * is0 * is1 * is2;
        bool c2 = (m22 >= m00) && (m22 >= m11);
        bool c1 = !c2 && (m11 >= m00);
        bool c0 = !c2 && !c1;
        is0 = c0 ? is0 * dd : is0;
        is1 = c1 ? is1 * dd : is1;
        is2 = c2 ? is2 * dd : is2;

        float w00 = is0 * v00 * v00 + is1 * v01 * v01 + is2 * v02 * v02;
        float w01 = is0 * v00 * v10 + is1 * v01 * v11 + is2 * v02 * v12;
        float w02 = is0 * v00 * v20 + is1 * v01 * v21 + is2 * v02 * v22;
        float w11 = is0 * v10 * v10 + is1 * v11 * v11 + is2 * v12 * v12;
        float w12 = is0 * v10 * v20 + is1 * v11 * v21 + is2 * v12 * v22;
        float w22 = is0 * v20 * v20 + is1 * v21 * v21 + is2 * v22 * v22;

        float r00 = a00 * w00 + a01 * w01 + a02 * w02;
        float r01 = a00 * w01 + a01 * w11 + a02 * w12;
        float r02 = a00 * w02 + a01 * w12 + a02 * w22;
        float r10 = a10 * w00 + a11 * w01 + a12 * w02;
        float r11 = a10 * w01 + a11 * w11 + a12 * w12;
        float r12 = a10 * w02 + a11 * w12 + a12 * w22;
        float r20 = a20 * w00 + a21 * w01 + a22 * w02;
        float r21 = a20 * w01 + a21 * w11 + a22 * w12;
        float r22 = a20 * w02 + a21 * w12 + a22 * w22;

        float nrg = 0.0f;
        const float* tvb = tevT + (size_t)v * 3 * maxd;
        for (int k = 0; k < maxd; ++k) {
            int j = adj_idx[v * maxd + k];
            float w = adj_w[v * maxd + k];
            float ex = predb[j] - p0x;
            float ey = predb[n + j] - p0y;
            float ez = predb[2 * n + j] - p0z;
            float tv0 = tvb[k];
            float tv1 = tvb[maxd + k];
            float tv2 = tvb[2 * maxd + k];
            float q0 = r00 * tv0 + r01 * tv1 + r02 * tv2;
            float q1 = r10 * tv0 + r11 * tv1 + r12 * tv2;
            float q2 = r20 * tv0 + r21 * tv1 + r22 * tv2;
            float dx = ex - q0, dy = ey - q1, dz = ez - q2;
            nrg += w * fsqrt_(dx * dx + dy * dy + dz * dz);
        }
        local += fminf(nrg, 1.0f);
    }

    float val = local;
    for (int off = 32; off > 0; off >>= 1)
        val += __shfl_down(val, off, 64);
    __shared__ float smf[NT / 64];
    int lane = threadIdx.x & 63, wid = threadIdx.x >> 6;
    if (lane == 0) smf[wid] = val;
    __syncthreads();
    if (threadIdx.x == 0)
        partials[(size_t)b * nblk_x + blockIdx.x] = smf[0] + smf[1] + smf[2] + smf[3];
}

__global__ __launch_bounds__(NT) void arap_reduce(
    const float* __restrict__ partials, float* __restrict__ out,
    int nblk_x, float inv_n)
{
    int b = blockIdx.x;
    float val = 0.0f;
    for (int i = threadIdx.x; i < nblk_x; i += NT)
        val += partials[(size_t)b * nblk_x + i];
    for (int off = 32; off > 0; off >>= 1)
        val += __shfl_down(val, off, 64);
    __shared__ float smf[NT / 64];
    int lane = threadIdx.x & 63, wid = threadIdx.x >> 6;
    if (lane == 0) smf[wid] = val;
    __syncthreads();
    if (threadIdx.x == 0)
        out[b] = (smf[0] + smf[1] + smf[2] + smf[3]) * inv_n;
}

extern "C" void kernel_launch(void* const* d_in, const int* in_sizes, int n_in,
                              void* d_out, int out_size, void* d_ws, size_t ws_size,
                              hipStream_t stream)
{
    const float* pred    = (const float*)d_in[0];
    const int*   adj_idx = (const int*)d_in[1];
    const float* adj_w   = (const float*)d_in[2];
    const float* tevT    = (const float*)d_in[3];
    const float* tevw    = (const float*)d_in[4];
    float* out = (float*)d_out;

    const int B = 16;
    const int n = in_sizes[0] / (3 * B);
    const int maxd = in_sizes[1] / n;

    int nblk = (n + NT - 1) / NT;
    long long ws_floats = (long long)(ws_size / sizeof(float));
    float* partials = (float*)d_ws;

    if (maxd == 6 && (long long)nblk * B <= ws_floats) {
        dim3 grid(nblk, NBSPLIT);
        arap_fused6<<<grid, NT, 0, stream>>>(pred, adj_idx, adj_w, tevT,
                                             partials, n, nblk);
        arap_reduce<<<B, NT, 0, stream>>>(partials, out, nblk,
                                          1.0f / (float)n);
    } else {
        int nblk_x = nblk;
        if ((long long)nblk_x * B > ws_floats) nblk_x = (int)(ws_floats / B);
        if (nblk_x < 1) nblk_x = 1;
        dim3 grid(nblk_x, B);
        arap_main<<<grid, NT, 0, stream>>>(pred, adj_idx, adj_w, tevT, tevw,
                                           partials, n, maxd, nblk_x);
        arap_reduce<<<B, NT, 0, stream>>>(partials, out, nblk_x,
                                          1.0f / (float)n);
    }
}

// Round 16
// 44.684 us; speedup vs baseline: 1.3204x; 1.3204x over previous
//
#include <hip/hip_runtime.h>
#include <math.h>

#define NT 256
#define NBSPLIT 4
#define NB (16 / NBSPLIT)
#define NSWEEPS 4   // fallback kernel only

__device__ __forceinline__ float fsqrt_(float x) { return __builtin_amdgcn_sqrtf(x); }
__device__ __forceinline__ float frcp_(float x)  { return __builtin_amdgcn_rcpf(x); }
__device__ __forceinline__ float frsq_(float x)  { return __builtin_amdgcn_rsqf(x); }

// maxd==6 specialized: single-chain POLAR-NEWTON (r13 base) + TRIMMED flip.
// Structure history: dual-chain ILP is a dead end on this compiler
// (r7: serialized at ~150 live; r14/r15: lands at VGPR=132 > 128 cliff
// regardless of what we move to LDS). r13 (46.1us, VGPR 100, 4 waves/SIMD)
// is the best verified base.
// r16 trim (validated for accuracy by r14/r15 passing runs, absmax 0.0039):
//   - lam1 from the PLAIN quadratic lam^2 - c2 lam + c1 (lam3 quartically
//     small on det<0 lanes; drops the lam3-deflation rcp).
//   - single-column projector: diag(G)=diag(M^2 - sft*M) -> argmax k ->
//     v1 = (M - sft I) (M e_k), one matvec instead of full M^2 (drops the
//     c0/lam rcp and ~10 ops). Flip chain: 4 trans -> 2 trans.
// Flip applied branchlessly AFTER Newton: X -= s*(X v1) v1^T, s = det<0?2:0;
// v1+s (4 regs) are all that cross the Newton section (r12 structure).
// Newton: 2 Frobenius-scaled + 2 unscaled, IN PLACE on A (scale-invariant;
// 2+1 is NOT enough — sigma-err ~2e-2 would eat the absmax headroom).
// Degenerate corners (A~0): NaN -> fminf(NaN,1)=1, error <= 2/n.
// NO launch_bounds min-waves pin (r4/r5: catastrophic spill). No atomics (r11).
__global__ __launch_bounds__(NT) void arap_fused6(
    const float* __restrict__ pred,      // (B, 3, n)
    const int*   __restrict__ adj_idx,   // (n, 6)
    const float* __restrict__ adj_w,     // (n, 6)
    const float* __restrict__ tevT,      // (n, 3, 6)
    float* __restrict__ partials,        // (B, nblk_x)
    int n, int nblk_x)
{
    __shared__ float tvs[18][NT];        // thread-private column, no barriers
    __shared__ float sm[NT / 64][NB];

    const int tid = threadIdx.x;
    const int v = blockIdx.x * NT + tid;
    const bool active = (v < n);
    const int vc = active ? v : 0;
    const int b0 = blockIdx.y * NB;

    int   jo[6];
    float wgt[6];
    {
        const int2* ai = (const int2*)(adj_idx + (size_t)vc * 6);
        int2 q0 = ai[0], q1 = ai[1], q2 = ai[2];
        jo[0] = q0.x; jo[1] = q0.y; jo[2] = q1.x;
        jo[3] = q1.y; jo[4] = q2.x; jo[5] = q2.y;
        const float2* aw = (const float2*)(adj_w + (size_t)vc * 6);
        float2 w0 = aw[0], w1 = aw[1], w2 = aw[2];
        wgt[0] = w0.x; wgt[1] = w0.y; wgt[2] = w1.x;
        wgt[3] = w1.y; wgt[4] = w2.x; wgt[5] = w2.y;
        const float2* tv = (const float2*)(tevT + (size_t)vc * 18);
        #pragma unroll
        for (int i = 0; i < 9; ++i) {
            float2 t = tv[i];
            tvs[2 * i][tid]     = t.x;
            tvs[2 * i + 1][tid] = t.y;
        }
    }

    const int lane = tid & 63, wid = tid >> 6;

    #pragma unroll 1
    for (int bi = 0; bi < NB; ++bi) {
        const float* __restrict__ predb = pred + (size_t)(b0 + bi) * 3 * n;
        const float p0x = predb[vc];
        const float p0y = predb[n + vc];
        const float p0z = predb[2 * n + vc];

        // Pass 1: gather edges (cached for pass 2); X = A = pred_ev @ (w*tevT^T)
        float ex[6], ey[6], ez[6];
        float x00 = 0.f, x01 = 0.f, x02 = 0.f;
        float x10 = 0.f, x11 = 0.f, x12 = 0.f;
        float x20 = 0.f, x21 = 0.f, x22 = 0.f;
        #pragma unroll
        for (int k = 0; k < 6; ++k) {
            int j = jo[k];
            float exk = predb[j]         - p0x;
            float eyk = predb[n + j]     - p0y;
            float ezk = predb[2 * n + j] - p0z;
            ex[k] = exk; ey[k] = eyk; ez[k] = ezk;
            float t0 = tvs[k][tid], t1 = tvs[6 + k][tid], t2 = tvs[12 + k][tid];
            float w = wgt[k];
            float fx = w * exk, fy = w * eyk, fz = w * ezk;
            x00 += fx * t0; x01 += fx * t1; x02 += fx * t2;
            x10 += fy * t0; x11 += fy * t1; x12 += fy * t2;
            x20 += fz * t0; x21 += fz * t1; x22 += fz * t2;
        }

        float detA = x00 * (x11 * x22 - x21 * x12)
                   - x10 * (x01 * x22 - x21 * x02)
                   + x20 * (x01 * x12 - x11 * x02);

        // ---- hoisted flip precompute (TRIMMED): v1 = argmax eigvec of
        // M = A^T A via plain quadratic + single projector column.
        // Only {v1, s} cross the Newton section. ----
        float vx, vy, vz, s;
        {
            float m00 = x00 * x00 + x10 * x10 + x20 * x20;
            float m01 = x00 * x01 + x10 * x11 + x20 * x21;
            float m02 = x00 * x02 + x10 * x12 + x20 * x22;
            float m11 = x01 * x01 + x11 * x11 + x21 * x21;
            float m12 = x01 * x02 + x11 * x12 + x21 * x22;
            float m22 = x02 * x02 + x12 * x12 + x22 * x22;
            float c2s = m00 + m11 + m22;
            float c1s = m00 * m11 - m01 * m01 + m00 * m22 - m02 * m02
                      + m11 * m22 - m12 * m12;
            float disc = fmaxf(c2s * c2s - 4.0f * c1s, 0.0f);
            float lam = 0.5f * (c2s + fsqrt_(disc));
            float sft = c2s - lam;
            // diag(G), G = M^2 - sft*M  (∝ v1 v1^T on flip lanes)
            float d0 = m00 * m00 + m01 * m01 + m02 * m02 - sft * m00;
            float d1 = m01 * m01 + m11 * m11 + m12 * m12 - sft * m11;
            float d2 = m02 * m02 + m12 * m12 + m22 * m22 - sft * m22;
            bool k1 = (d1 > d0) && (d1 >= d2);
            bool k2 = (d2 > d0) && (d2 > d1);
            // a = column argmax of M (symmetric -> row)
            float a0 = k1 ? m01 : (k2 ? m02 : m00);
            float a1 = k1 ? m11 : (k2 ? m12 : m01);
            float a2 = k1 ? m12 : (k2 ? m22 : m02);
            // v1 ∝ G e_k = (M - sft I) a
            vx = m00 * a0 + m01 * a1 + m02 * a2 - sft * a0;
            vy = m01 * a0 + m11 * a1 + m12 * a2 - sft * a1;
            vz = m02 * a0 + m12 * a1 + m22 * a2 - sft * a2;
            float inv = frsq_(fmaxf(vx * vx + vy * vy + vz * vz, 1e-30f));
            vx *= inv; vy *= inv; vz *= inv;
            s = (detA < 0.0f) ? 2.0f : 0.0f;
        }

        // ---- scaled Newton, IN PLACE on A (scale-invariant, no X0 norm) ----
        #pragma unroll
        for (int it = 0; it < 2; ++it) {
            float c00 = x11 * x22 - x21 * x12;
            float c01 = x12 * x20 - x10 * x22;
            float c02 = x10 * x21 - x11 * x20;
            float c10 = x02 * x21 - x01 * x22;
            float c11 = x00 * x22 - x02 * x20;
            float c12 = x01 * x20 - x00 * x21;
            float c20 = x01 * x12 - x02 * x11;
            float c21 = x02 * x10 - x00 * x12;
            float c22 = x00 * x11 - x01 * x10;
            float det = x00 * c00 + x01 * c01 + x02 * c02;
            float nX = x00 * x00 + x01 * x01 + x02 * x02
                     + x10 * x10 + x11 * x11 + x12 * x12
                     + x20 * x20 + x21 * x21 + x22 * x22;
            float nC = c00 * c00 + c01 * c01 + c02 * c02
                     + c10 * c10 + c11 * c11 + c12 * c12
                     + c20 * c20 + c21 * c21 + c22 * c22;
            float ratio = nC * frcp_(det * det * nX);
            float mu = fsqrt_(fsqrt_(ratio));
            float f1 = 0.5f * mu;
            float f2 = 0.5f * frcp_(mu * det);
            x00 = f1 * x00 + f2 * c00;
            x01 = f1 * x01 + f2 * c01;
            x02 = f1 * x02 + f2 * c02;
            x10 = f1 * x10 + f2 * c10;
            x11 = f1 * x11 + f2 * c11;
            x12 = f1 * x12 + f2 * c12;
            x20 = f1 * x20 + f2 * c20;
            x21 = f1 * x21 + f2 * c21;
            x22 = f1 * x22 + f2 * c22;
        }
        #pragma unroll
        for (int it = 0; it < 2; ++it) {
            float c00 = x11 * x22 - x21 * x12;
            float c01 = x12 * x20 - x10 * x22;
            float c02 = x10 * x21 - x11 * x20;
            float c10 = x02 * x21 - x01 * x22;
            float c11 = x00 * x22 - x02 * x20;
            float c12 = x01 * x20 - x00 * x21;
            float c20 = x01 * x12 - x02 * x11;
            float c21 = x02 * x10 - x00 * x12;
            float c22 = x00 * x11 - x01 * x10;
            float det = x00 * c00 + x01 * c01 + x02 * c02;
            float f2 = 0.5f * frcp_(det);
            x00 = 0.5f * x00 + f2 * c00;
            x01 = 0.5f * x01 + f2 * c01;
            x02 = 0.5f * x02 + f2 * c02;
            x10 = 0.5f * x10 + f2 * c10;
            x11 = 0.5f * x11 + f2 * c11;
            x12 = 0.5f * x12 + f2 * c12;
            x20 = 0.5f * x20 + f2 * c20;
            x21 = 0.5f * x21 + f2 * c21;
            x22 = 0.5f * x22 + f2 * c22;
        }

        // ---- branchless flip: X -= s * (X v1) v1^T  (s = 0 or 2) ----
        float ux = x00 * vx + x01 * vy + x02 * vz;
        float uy = x10 * vx + x11 * vy + x12 * vz;
        float uz = x20 * vx + x21 * vy + x22 * vz;
        ux *= s; uy *= s; uz *= s;
        x00 -= ux * vx; x01 -= ux * vy; x02 -= ux * vz;
        x10 -= uy * vx; x11 -= uy * vy; x12 -= uy * vz;
        x20 -= uz * vx; x21 -= uz * vy; x22 -= uz * vz;

        // Pass 2: energy from cached edges
        float nrg = 0.0f;
        #pragma unroll
        for (int k = 0; k < 6; ++k) {
            float t0 = tvs[k][tid], t1 = tvs[6 + k][tid], t2 = tvs[12 + k][tid];
            float q0 = x00 * t0 + x01 * t1 + x02 * t2;
            float q1 = x10 * t0 + x11 * t1 + x12 * t2;
            float q2 = x20 * t0 + x21 * t1 + x22 * t2;
            float dx = ex[k] - q0, dy = ey[k] - q1, dz = ez[k] - q2;
            nrg += wgt[k] * fsqrt_(dx * dx + dy * dy + dz * dz);
        }
        float val = active ? fminf(nrg, 1.0f) : 0.0f;

        #pragma unroll
        for (int off = 32; off > 0; off >>= 1)
            val += __shfl_down(val, off, 64);
        if (lane == 0) sm[wid][bi] = val;
    }

    __syncthreads();
    if (tid < NB) {
        float sacc = 0.0f;
        #pragma unroll
        for (int w = 0; w < NT / 64; ++w) sacc += sm[w][tid];
        partials[(size_t)(b0 + tid) * nblk_x + blockIdx.x] = sacc;
    }
}

// ---------------- generic fallback (Jacobi path) ----------------
__device__ __forceinline__ void jrot(float& app, float& aqq, float& apq,
                                     float& arp, float& arq,
                                     float& vp0, float& vp1, float& vp2,
                                     float& vq0, float& vq1, float& vq2)
{
    float a = apq;
    float scale = fabsf(app) + fabsf(aqq);
    if (fabsf(a) > 1e-12f * scale + 1e-35f) {
        float h = aqq - app;
        float r = fsqrt_(fmaf(h, h, 4.0f * a * a));
        float den = fabsf(h) + r;
        float t2a = (h >= 0.0f) ? 2.0f * a : -2.0f * a;
        float t = t2a * frcp_(den);
        float c = frsq_(fmaf(t, t, 1.0f));
        float s = t * c;
        app -= t * a;
        aqq += t * a;
        apq = 0.0f;
        float rp = arp, rq = arq;
        arp = c * rp - s * rq;
        arq = s * rp + c * rq;
        float x, y;
        x = vp0; y = vq0; vp0 = c * x - s * y; vq0 = s * x + c * y;
        x = vp1; y = vq1; vp1 = c * x - s * y; vq1 = s * x + c * y;
        x = vp2; y = vq2; vp2 = c * x - s * y; vq2 = s * x + c * y;
    }
}

__global__ __launch_bounds__(NT) void arap_main(
    const float* __restrict__ pred, const int* __restrict__ adj_idx,
    const float* __restrict__ adj_w, const float* __restrict__ tevT,
    const float* __restrict__ tevw, float* __restrict__ partials,
    int n, int maxd, int nblk_x)
{
    const int b = blockIdx.y;
    const float* __restrict__ predb = pred + (size_t)b * 3 * n;
    float local = 0.0f;

    for (int v = blockIdx.x * NT + threadIdx.x; v < n; v += nblk_x * NT) {
        const float p0x = predb[v];
        const float p0y = predb[n + v];
        const float p0z = predb[2 * n + v];

        float a00 = 0.f, a01 = 0.f, a02 = 0.f;
        float a10 = 0.f, a11 = 0.f, a12 = 0.f;
        float a20 = 0.f, a21 = 0.f, a22 = 0.f;
        for (int k = 0; k < maxd; ++k) {
            int j = adj_idx[v * maxd + k];
            float ex = predb[j] - p0x;
            float ey = predb[n + j] - p0y;
            float ez = predb[2 * n + j] - p0z;
            const float* tw = tevw + ((size_t)v * maxd + k) * 3;
            float t0 = tw[0], t1 = tw[1], t2 = tw[2];
            a00 += ex * t0; a01 += ex * t1; a02 += ex * t2;
            a10 += ey * t0; a11 += ey * t1; a12 += ey * t2;
            a20 += ez * t0; a21 += ez * t1; a22 += ez * t2;
        }
        const float stab = 1000.0f;
        a00 *= stab; a01 *= stab; a02 *= stab;
        a10 *= stab; a11 *= stab; a12 *= stab;
        a20 *= stab; a21 *= stab; a22 *= stab;

        float m00 = a00 * a00 + a10 * a10 + a20 * a20;
        float m01 = a00 * a01 + a10 * a11 + a20 * a21;
        float m02 = a00 * a02 + a10 * a12 + a20 * a22;
        float m11 = a01 * a01 + a11 * a11 + a21 * a21;
        float m12 = a01 * a02 + a11 * a12 + a21 * a22;
        float m22 = a02 * a02 + a12 * a12 + a22 * a22;

        float v00 = 1.f, v01 = 0.f, v02 = 0.f;
        float v10 = 0.f, v11 = 1.f, v12 = 0.f;
        float v20 = 0.f, v21 = 0.f, v22 = 1.f;
        #pragma unroll
        for (int sweep = 0; sweep < NSWEEPS; ++sweep) {
            jrot(m00, m11, m01, m02, m12, v00, v10, v20, v01, v11, v21);
            jrot(m00, m22, m02, m01, m12, v00, v10, v20, v02, v12, v22);
            jrot(m11, m22, m12, m01, m02, v01, v11, v21, v02, v12, v22);
        }

        float is0 = frsq_(fmaxf(m00, 1e-6f));
        float is1 = frsq_(fmaxf(m11, 1e-6f));
        float is2 = frsq_(fmaxf(m22, 1e-6f));
        float detA = a00 * (a11 * a22 - a21 * a12)
                   - a10 * (a01 * a22 - a21 * a02)
                   + a20 * (a01 * a12 - a11 * a02);
        float dd = detA * is0 * is1 * is2;
        bool c2 = (m22 >= m00) && (m22 >= m11);
        bool c1 = !c2 && (m11 >= m00);
        bool c0 = !c2 && !c1;
        is0 = c0 ? is0 * dd : is0;
        is1 = c1 ? is1 * dd : is1;
        is2 = c2 ? is2 * dd : is2;

        float w00 = is0 * v00 * v00 + is1 * v01 * v01 + is2 * v02 * v02;
        float w01 = is0 * v00 * v10 + is1 * v01 * v11 + is2 * v02 * v12;
        float w02 = is0 * v00 * v20 + is1 * v01 * v21 + is2 * v02 * v22;
        float w11 = is0 * v10 * v10 + is1 * v11 * v11 + is2 * v12 * v12;
        float w12 = is0 * v10 * v20 + is1 * v11 * v21 + is2 * v12 * v22;
        float w22 = is0 * v20 * v20 + is1 * v21 * v21 + is2 * v22 * v22;

        float r00 = a00 * w00 + a01 * w01 + a02 * w02;
        float r01 = a00 * w01 + a01 * w11 + a02 * w12;
        float r02 = a00 * w02 + a01 * w12 + a02 * w22;
        float r10 = a10 * w00 + a11 * w01 + a12 * w02;
        float r11 = a10 * w01 + a11 * w11 + a12 * w12;
        float r12 = a10 * w02 + a11 * w12 + a12 * w22;
        float r20 = a20 * w00 + a21 * w01 + a22 * w02;
        float r21 = a20 * w01 + a21 * w11 + a22 * w12;
        float r22 = a20 * w02 + a21 * w12 + a22 * w22;

        float nrg = 0.0f;
        const float* tvb = tevT + (size_t)v * 3 * maxd;
        for (int k = 0; k < maxd; ++k) {
            int j = adj_idx[v * maxd + k];
            float w = adj_w[v * maxd + k];
            float ex = predb[j] - p0x;
            float ey = predb[n + j] - p0y;
            float ez = predb[2 * n + j] - p0z;
            float tv0 = tvb[k];
            float tv1 = tvb[maxd + k];
            float tv2 = tvb[2 * maxd + k];
            float q0 = r00 * tv0 + r01 * tv1 + r02 * tv2;
            float q1 = r10 * tv0 + r11 * tv1 + r12 * tv2;
            float q2 = r20 * tv0 + r21 * tv1 + r22 * tv2;
            float dx = ex - q0, dy = ey - q1, dz = ez - q2;
            nrg += w * fsqrt_(dx * dx + dy * dy + dz * dz);
        }
        local += fminf(nrg, 1.0f);
    }

    float val = local;
    for (int off = 32; off > 0; off >>= 1)
        val += __shfl_down(val, off, 64);
    __shared__ float smf[NT / 64];
    int lane = threadIdx.x & 63, wid = threadIdx.x >> 6;
    if (lane == 0) smf[wid] = val;
    __syncthreads();
    if (threadIdx.x == 0)
        partials[(size_t)b * nblk_x + blockIdx.x] = smf[0] + smf[1] + smf[2] + smf[3];
}

__global__ __launch_bounds__(NT) void arap_reduce(
    const float* __restrict__ partials, float* __restrict__ out,
    int nblk_x, float inv_n)
{
    int b = blockIdx.x;
    float val = 0.0f;
    for (int i = threadIdx.x; i < nblk_x; i += NT)
        val += partials[(size_t)b * nblk_x + i];
    for (int off = 32; off > 0; off >>= 1)
        val += __shfl_down(val, off, 64);
    __shared__ float smf[NT / 64];
    int lane = threadIdx.x & 63, wid = threadIdx.x >> 6;
    if (lane == 0) smf[wid] = val;
    __syncthreads();
    if (threadIdx.x == 0)
        out[b] = (smf[0] + smf[1] + smf[2] + smf[3]) * inv_n;
}

extern "C" void kernel_launch(void* const* d_in, const int* in_sizes, int n_in,
                              void* d_out, int out_size, void* d_ws, size_t ws_size,
                              hipStream_t stream)
{
    const float* pred    = (const float*)d_in[0];
    const int*   adj_idx = (const int*)d_in[1];
    const float* adj_w   = (const float*)d_in[2];
    const float* tevT    = (const float*)d_in[3];
    const float* tevw    = (const float*)d_in[4];
    float* out = (float*)d_out;

    const int B = 16;
    const int n = in_sizes[0] / (3 * B);
    const int maxd = in_sizes[1] / n;

    int nblk = (n + NT - 1) / NT;
    long long ws_floats = (long long)(ws_size / sizeof(float));
    float* partials = (float*)d_ws;

    if (maxd == 6 && (long long)nblk * B <= ws_floats) {
        dim3 grid(nblk, NBSPLIT);
        arap_fused6<<<grid, NT, 0, stream>>>(pred, adj_idx, adj_w, tevT,
                                             partials, n, nblk);
        arap_reduce<<<B, NT, 0, stream>>>(partials, out, nblk,
                                          1.0f / (float)n);
    } else {
        int nblk_x = nblk;
        if ((long long)nblk_x * B > ws_floats) nblk_x = (int)(ws_floats / B);
        if (nblk_x < 1) nblk_x = 1;
        dim3 grid(nblk_x, B);
        arap_main<<<grid, NT, 0, stream>>>(pred, adj_idx, adj_w, tevT, tevw,
                                           partials, n, maxd, nblk_x);
        arap_reduce<<<B, NT, 0, stream>>>(partials, out, nblk_x,
                                          1.0f / (float)n);
    }
}